// Round 6
// baseline (441.860 us; speedup 1.0000x reference)
//
#include <hip/hip_runtime.h>
#include <hip/hip_bf16.h>

#define B_SZ   2
#define T_SEQ  2048
#define C_EMB  2048
#define KV_DIM 512

typedef __bf16 bf16x8 __attribute__((ext_vector_type(8)));
typedef __bf16 bf16x4 __attribute__((ext_vector_type(4)));
typedef float  f32x4  __attribute__((ext_vector_type(4)));
typedef float  f32x16 __attribute__((ext_vector_type(16)));
typedef unsigned int u32;

typedef __attribute__((address_space(1))) const unsigned int gu32;
typedef __attribute__((address_space(3))) unsigned int lu32;
__device__ __forceinline__ void gload16(const void* g, void* l) {
  __builtin_amdgcn_global_load_lds((gu32*)g, (lu32*)l, 16, 0, 0);
}

// ---------------- cast f32 -> bf16 (vectorized) ----------------
__global__ __launch_bounds__(256) void cast_f32_bf16(const float* __restrict__ in,
                                                     __bf16* __restrict__ out, int n8) {
  int i = blockIdx.x * 256 + threadIdx.x;
  if (i < n8) {
    const float4* p = (const float4*)(in + (size_t)i * 8);
    float4 a = p[0], b = p[1];
    bf16x8 o;
    o[0] = (__bf16)a.x; o[1] = (__bf16)a.y; o[2] = (__bf16)a.z; o[3] = (__bf16)a.w;
    o[4] = (__bf16)b.x; o[5] = (__bf16)b.y; o[6] = (__bf16)b.z; o[7] = (__bf16)b.w;
    *(bf16x8*)(out + (size_t)i * 8) = o;
  }
}

// ---------------- transpose + cast: in[R][C] f32 -> out[C][R] bf16 ----------------
__global__ __launch_bounds__(256) void transpose_cast_kernel(const float* __restrict__ in,
                                                             __bf16* __restrict__ out,
                                                             int R, int C) {
  __shared__ float tile[64][65];
  int c0 = blockIdx.x * 64, r0 = blockIdx.y * 64;
  int tid = threadIdx.x;
#pragma unroll
  for (int i = 0; i < 4; i++) {
    int idx = tid + i * 256;
    int row = idx >> 4;
    int c4  = (idx & 15) * 4;
    float4 v = *(const float4*)&in[(size_t)(r0 + row) * C + c0 + c4];
    tile[row][c4 + 0] = v.x; tile[row][c4 + 1] = v.y;
    tile[row][c4 + 2] = v.z; tile[row][c4 + 3] = v.w;
  }
  __syncthreads();
#pragma unroll
  for (int i = 0; i < 4; i++) {
    int idx = tid + i * 256;
    int col = idx >> 4;
    int r4  = (idx & 15) * 4;
    bf16x4 o;
    o[0] = (__bf16)tile[r4 + 0][col];
    o[1] = (__bf16)tile[r4 + 1][col];
    o[2] = (__bf16)tile[r4 + 2][col];
    o[3] = (__bf16)tile[r4 + 3][col];
    *(bf16x4*)&out[(size_t)(c0 + col) * R + r0 + r4] = o;
  }
}

__global__ __launch_bounds__(256) void concat_bias(const float* __restrict__ bq,
                                                   const float* __restrict__ bk,
                                                   const float* __restrict__ bv,
                                                   float* __restrict__ bcat) {
  int i = blockIdx.x * 256 + threadIdx.x;
  if (i < 3072) {
    float v = (i < 2048) ? bq[i] : (i < 2560 ? bk[i - 2048] : bv[i - 2560]);
    bcat[i] = v;
  }
}

// ---------------- GEMM: C[M][N] = A[M][K] * Bt[N][K]^T + bias ----------------
// 128x128 tile, BK=32, 4 waves, global_load_lds staging (m97 structure).
// MODE 1: fused QKV epilogue (Q prescaled by 0.125*log2e, K row-major, V transposed).
// MODE 2: f32 row-major out.
template <int MODE>
__global__ __launch_bounds__(256) void gemm_bt(const __bf16* __restrict__ A,
                                               const __bf16* __restrict__ Bt,
                                               const float* __restrict__ bias,
                                               void* __restrict__ out0,
                                               __bf16* __restrict__ outK,
                                               __bf16* __restrict__ outV,
                                               int M, int N, int K) {
  __shared__ __bf16 As[128 * 32];
  __shared__ __bf16 Bs[128 * 32];
  int tid  = threadIdx.x;
  int lane = tid & 63, wave = tid >> 6;
  int wr = wave >> 1, wc = wave & 1;
  int la = lane & 15, kg = lane >> 4;
  int m0 = blockIdx.x * 128, n0 = blockIdx.y * 128;

  f32x4 acc[4][4];
#pragma unroll
  for (int i = 0; i < 4; i++)
#pragma unroll
    for (int j = 0; j < 4; j++)
#pragma unroll
      for (int r = 0; r < 4; r++) acc[i][j][r] = 0.f;

  int s0 = tid, s1 = tid + 256;
  const __bf16* ga0 = A  + (size_t)(m0 + (s0 >> 2)) * K + (s0 & 3) * 8;
  const __bf16* ga1 = A  + (size_t)(m0 + (s1 >> 2)) * K + (s1 & 3) * 8;
  const __bf16* gb0 = Bt + (size_t)(n0 + (s0 >> 2)) * K + (s0 & 3) * 8;
  const __bf16* gb1 = Bt + (size_t)(n0 + (s1 >> 2)) * K + (s1 & 3) * 8;
  __bf16* lA0 = As + (size_t)(0 * 256 + wave * 64) * 8;
  __bf16* lA1 = As + (size_t)(1 * 256 + wave * 64) * 8;
  __bf16* lB0 = Bs + (size_t)(0 * 256 + wave * 64) * 8;
  __bf16* lB1 = Bs + (size_t)(1 * 256 + wave * 64) * 8;

  for (int k0 = 0; k0 < K; k0 += 32) {
    gload16(ga0 + k0, lA0);
    gload16(ga1 + k0, lA1);
    gload16(gb0 + k0, lB0);
    gload16(gb1 + k0, lB1);
    __syncthreads();
    bf16x8 af[4], bfr[4];
#pragma unroll
    for (int i = 0; i < 4; i++) af[i]  = *(const bf16x8*)&As[(size_t)(wr * 64 + i * 16 + la) * 32 + kg * 8];
#pragma unroll
    for (int j = 0; j < 4; j++) bfr[j] = *(const bf16x8*)&Bs[(size_t)(wc * 64 + j * 16 + la) * 32 + kg * 8];
#pragma unroll
    for (int i = 0; i < 4; i++)
#pragma unroll
      for (int j = 0; j < 4; j++)
        acc[i][j] = __builtin_amdgcn_mfma_f32_16x16x32_bf16(af[i], bfr[j], acc[i][j], 0, 0, 0);
    __syncthreads();
  }

#pragma unroll
  for (int i = 0; i < 4; i++) {
    int rowb = m0 + wr * 64 + i * 16 + kg * 4;
#pragma unroll
    for (int j = 0; j < 4; j++) {
      int col = n0 + wc * 64 + j * 16 + la;
      float bv = bias[col];
#pragma unroll
      for (int r = 0; r < 4; r++) {
        float v = acc[i][j][r] + bv;
        if (MODE == 2) {
          ((float*)out0)[(size_t)(rowb + r) * N + col] = v;
        } else {
          if (n0 < 2048)      ((__bf16*)out0)[(size_t)(rowb + r) * 2048 + col] = (__bf16)(v * 0.18033688f);
          else if (n0 < 2560) outK[(size_t)(rowb + r) * 512 + (col - 2048)] = (__bf16)v;
          else                outV[(size_t)(col - 2560) * M + rowb + r] = (__bf16)v;
        }
      }
    }
  }
}

// ---------------- flash GQA attention, swapped-operand 32x32 ----------------
// 2 waves/block, 32 queries/wave. S^T = mfma(K,Q) (Q prescaled by 0.125*log2e).
// PV swapped: Y^T = mfma(V^T, P^T) with a PERMUTED k-slot order chosen so each
// lane's owned S^T rows ARE its B-fragment slots (zero cross-lane redistribution);
// V^T is loaded with the same permutation (2x8B loads per fragment).
__global__ __launch_bounds__(128) void attn_kernel(const __bf16* __restrict__ Q,
                                                   const __bf16* __restrict__ K,
                                                   const __bf16* __restrict__ Vt,
                                                   __bf16* __restrict__ Y) {
  __shared__ __bf16 Ylds[2][32][72];
  const int M = B_SZ * T_SEQ;
  int tid = threadIdx.x;
  int wv = tid >> 6, l = tid & 63;
  int qcol = l & 31, hh = l >> 5;
  int g = blockIdx.x;
  int qt = 31 - (g >> 6);           // heavy-first (LPT) dispatch order
  int bh = g & 63;
  int b = bh >> 5, hq = bh & 31, kvh = hq >> 2;
  int q0w = qt * 64 + wv * 32;

  const __bf16* qrow = Q + (size_t)(b * T_SEQ + q0w + qcol) * C_EMB + hq * 64;
  bf16x8 qf[4];
#pragma unroll
  for (int c = 0; c < 4; c++) qf[c] = *(const bf16x8*)(qrow + c * 16 + hh * 8);

  f32x16 acc0, acc1;
#pragma unroll
  for (int r = 0; r < 16; r++) { acc0[r] = 0.f; acc1[r] = 0.f; }
  float m_run = -1e30f, l_run = 0.f;

  const __bf16* kbase = K + (size_t)(b * T_SEQ + qcol) * KV_DIM + kvh * 64 + hh * 8;
  // V bases include the permutation's +4*hh key offset
  const __bf16* vb0 = Vt + (size_t)(kvh * 64 + qcol) * M + (size_t)b * T_SEQ + 4 * hh;
  const __bf16* vb1 = vb0 + (size_t)32 * M;

  bf16x8 kf[4];
#pragma unroll
  for (int c = 0; c < 4; c++) kf[c] = *(const bf16x8*)(kbase + c * 16);

  for (int kb = 0; kb <= q0w; kb += 32) {
    // ---- S^T[32k x 32q] over d=64
    f32x16 s;
#pragma unroll
    for (int r = 0; r < 16; r++) s[r] = 0.f;
    __builtin_amdgcn_s_setprio(1);
#pragma unroll
    for (int c = 0; c < 4; c++)
      s = __builtin_amdgcn_mfma_f32_32x32x16_bf16(kf[c], qf[c], s, 0, 0, 0);
    __builtin_amdgcn_s_setprio(0);
    // ---- prefetch next K tile (clamped; wasted only on last iter)
    {
      int nkb = (kb + 32 <= q0w) ? kb + 32 : 0;
      const __bf16* nk = kbase + (size_t)nkb * KV_DIM;
#pragma unroll
      for (int c = 0; c < 4; c++) kf[c] = *(const bf16x8*)(nk + c * 16);
    }
    // ---- V fragment loads, permuted key order: slot(hh,j) <-> key (j&3)+8*(j>>2)+4*hh
    // Each fragment = two 8B loads: keys {kb+s16+4hh..+3} and {kb+s16+8+4hh..+3}.
    union { bf16x4 h[2]; bf16x8 v; } va00, va01, va10, va11;
    va00.h[0] = *(const bf16x4*)(vb0 + kb);
    va00.h[1] = *(const bf16x4*)(vb0 + kb + 8);
    va01.h[0] = *(const bf16x4*)(vb0 + kb + 16);
    va01.h[1] = *(const bf16x4*)(vb0 + kb + 24);
    va10.h[0] = *(const bf16x4*)(vb1 + kb);
    va10.h[1] = *(const bf16x4*)(vb1 + kb + 8);
    va11.h[0] = *(const bf16x4*)(vb1 + kb + 16);
    va11.h[1] = *(const bf16x4*)(vb1 + kb + 24);
    // ---- causal mask (diagonal tile only)
    if (kb == q0w) {
#pragma unroll
      for (int r = 0; r < 16; r++) {
        int kr = (r & 3) + 8 * (r >> 2) + 4 * hh;
        s[r] = (kr <= qcol) ? s[r] : -1e30f;
      }
    }
    // ---- row max: in-register tree + one cross-half shuffle
    float m01 = fmaxf(s[0], s[1]),  m23 = fmaxf(s[2], s[3]);
    float m45 = fmaxf(s[4], s[5]),  m67 = fmaxf(s[6], s[7]);
    float m89 = fmaxf(s[8], s[9]),  mab = fmaxf(s[10], s[11]);
    float mcd = fmaxf(s[12], s[13]), mef = fmaxf(s[14], s[15]);
    float mloc = fmaxf(fmaxf(fmaxf(m01, m23), fmaxf(m45, m67)),
                       fmaxf(fmaxf(m89, mab), fmaxf(mcd, mef)));
    mloc = fmaxf(mloc, __shfl_xor(mloc, 32, 64));
    // ---- deferred rescale (log2 domain; p <= 2^6)
    if (__any(mloc > m_run + 6.0f)) {
      float mnew = fmaxf(m_run, mloc);
      float corr = exp2f(m_run - mnew);
      l_run *= corr;
#pragma unroll
      for (int r = 0; r < 16; r++) { acc0[r] *= corr; acc1[r] *= corr; }
      m_run = mnew;
    }
    // ---- P = exp2(s - m) in place; tree partial row sum (finished in epilogue)
#pragma unroll
    for (int r = 0; r < 16; r++) s[r] = exp2f(s[r] - m_run);
    l_run += (((s[0] + s[1]) + (s[2] + s[3])) + ((s[4] + s[5]) + (s[6] + s[7])))
           + (((s[8] + s[9]) + (s[10] + s[11])) + ((s[12] + s[13]) + (s[14] + s[15])));
    // ---- pack own 16 P-values straight into the two B-fragments (no shuffles)
    union { u32 u[4]; bf16x8 v; } w0u, w1u;
#pragma unroll
    for (int j = 0; j < 4; j++) {
      union { __bf16 b2[2]; u32 u; } p0, p1;
      p0.b2[0] = (__bf16)s[2 * j];     p0.b2[1] = (__bf16)s[2 * j + 1];
      p1.b2[0] = (__bf16)s[8 + 2 * j]; p1.b2[1] = (__bf16)s[9 + 2 * j];
      w0u.u[j] = p0.u;
      w1u.u[j] = p1.u;
    }
    // ---- PV: Y^T += V^T * P^T (same permuted k order on both operands)
    __builtin_amdgcn_s_setprio(1);
    acc0 = __builtin_amdgcn_mfma_f32_32x32x16_bf16(va00.v, w0u.v, acc0, 0, 0, 0);
    acc0 = __builtin_amdgcn_mfma_f32_32x32x16_bf16(va01.v, w1u.v, acc0, 0, 0, 0);
    acc1 = __builtin_amdgcn_mfma_f32_32x32x16_bf16(va10.v, w0u.v, acc1, 0, 0, 0);
    acc1 = __builtin_amdgcn_mfma_f32_32x32x16_bf16(va11.v, w1u.v, acc1, 0, 0, 0);
    __builtin_amdgcn_s_setprio(0);
  }

  // ---- finish row sum across halves, normalize, LDS transpose, 16B stores
  l_run += __shfl_xor(l_run, 32, 64);
  float inv = 1.0f / l_run;
  __bf16 (*slab)[72] = Ylds[wv];
#pragma unroll
  for (int r = 0; r < 16; r++) {
    int drow = (r & 3) + 8 * (r >> 2) + 4 * hh;
    slab[qcol][drow]      = (__bf16)(acc0[r] * inv);
    slab[qcol][32 + drow] = (__bf16)(acc1[r] * inv);
  }
  __syncthreads();
  __bf16* yrow = Y + (size_t)(b * T_SEQ + q0w + qcol) * C_EMB + hq * 64 + hh * 32;
#pragma unroll
  for (int c = 0; c < 4; c++)
    *(bf16x8*)(yrow + c * 8) = *(const bf16x8*)&slab[qcol][hh * 32 + c * 8];
}

// ---------------- launch ----------------
extern "C" void kernel_launch(void* const* d_in, const int* in_sizes, int n_in,
                              void* d_out, int out_size, void* d_ws, size_t ws_size,
                              hipStream_t stream) {
  const float* x  = (const float*)d_in[0];
  const float* Wq = (const float*)d_in[1];
  const float* bq = (const float*)d_in[2];
  const float* Wk = (const float*)d_in[3];
  const float* bk = (const float*)d_in[4];
  const float* Wv = (const float*)d_in[5];
  const float* bv = (const float*)d_in[6];
  const float* Wo = (const float*)d_in[7];
  const float* bo = (const float*)d_in[8];
  float* out = (float*)d_out;

  const int M = B_SZ * T_SEQ;       // 4096

  char* w = (char*)d_ws;
  __bf16* xb   = (__bf16*)w; w += (size_t)M * C_EMB * 2;
  __bf16* Wall = (__bf16*)w; w += (size_t)3072 * C_EMB * 2;   // [Wq^T; Wk^T; Wv^T]
  __bf16* Wot  = (__bf16*)w; w += (size_t)C_EMB * C_EMB * 2;
  float*  bcat = (float*)w;  w += (size_t)3072 * 4;
  __bf16* qb   = (__bf16*)w; w += (size_t)M * C_EMB * 2;
  __bf16* kbf  = (__bf16*)w; w += (size_t)M * KV_DIM * 2;
  __bf16* vbt  = (__bf16*)w; w += (size_t)KV_DIM * M * 2;
  __bf16* yb   = (__bf16*)w; w += (size_t)M * C_EMB * 2;

  cast_f32_bf16<<<(M * C_EMB / 8 + 255) / 256, 256, 0, stream>>>(x, xb, M * C_EMB / 8);

  transpose_cast_kernel<<<dim3(C_EMB / 64, C_EMB / 64), 256, 0, stream>>>(Wq, Wall, C_EMB, C_EMB);
  transpose_cast_kernel<<<dim3(KV_DIM / 64, C_EMB / 64), 256, 0, stream>>>(Wk, Wall + (size_t)2048 * C_EMB, C_EMB, KV_DIM);
  transpose_cast_kernel<<<dim3(KV_DIM / 64, C_EMB / 64), 256, 0, stream>>>(Wv, Wall + (size_t)2560 * C_EMB, C_EMB, KV_DIM);
  transpose_cast_kernel<<<dim3(C_EMB / 64, C_EMB / 64), 256, 0, stream>>>(Wo, Wot, C_EMB, C_EMB);
  concat_bias<<<12, 256, 0, stream>>>(bq, bk, bv, bcat);

  // fused QKV projection: [4096 x 3072] = xb * Wall^T
  gemm_bt<1><<<dim3(M / 128, 3072 / 128), 256, 0, stream>>>(xb, Wall, bcat, qb, kbf, vbt, M, 3072, C_EMB);

  attn_kernel<<<dim3(2048), 128, 0, stream>>>(qb, kbf, vbt, yb);

  gemm_bt<2><<<dim3(M / 128, C_EMB / 128), 256, 0, stream>>>(yb, Wot, bo, out, nullptr, nullptr, M, C_EMB, C_EMB);
}

// Round 8
// 377.823 us; speedup vs baseline: 1.1695x; 1.1695x over previous
//
#include <hip/hip_runtime.h>
#include <hip/hip_bf16.h>

#define B_SZ   2
#define T_SEQ  2048
#define C_EMB  2048
#define KV_DIM 512

typedef __bf16 bf16x8 __attribute__((ext_vector_type(8)));
typedef __bf16 bf16x4 __attribute__((ext_vector_type(4)));
typedef float  f32x4  __attribute__((ext_vector_type(4)));
typedef float  f32x16 __attribute__((ext_vector_type(16)));
typedef unsigned int u32;

typedef __attribute__((address_space(1))) const unsigned int gu32;
typedef __attribute__((address_space(3))) unsigned int lu32;
__device__ __forceinline__ void gload16(const void* g, void* l) {
  __builtin_amdgcn_global_load_lds((gu32*)g, (lu32*)l, 16, 0, 0);
}

// ---------------- cast f32 -> bf16 (vectorized) ----------------
__global__ __launch_bounds__(256) void cast_f32_bf16(const float* __restrict__ in,
                                                     __bf16* __restrict__ out, int n8) {
  int i = blockIdx.x * 256 + threadIdx.x;
  if (i < n8) {
    const float4* p = (const float4*)(in + (size_t)i * 8);
    float4 a = p[0], b = p[1];
    bf16x8 o;
    o[0] = (__bf16)a.x; o[1] = (__bf16)a.y; o[2] = (__bf16)a.z; o[3] = (__bf16)a.w;
    o[4] = (__bf16)b.x; o[5] = (__bf16)b.y; o[6] = (__bf16)b.z; o[7] = (__bf16)b.w;
    *(bf16x8*)(out + (size_t)i * 8) = o;
  }
}

// ---------------- transpose + cast: in[R][C] f32 -> out[C][R] bf16 ----------------
__global__ __launch_bounds__(256) void transpose_cast_kernel(const float* __restrict__ in,
                                                             __bf16* __restrict__ out,
                                                             int R, int C) {
  __shared__ float tile[64][65];
  int c0 = blockIdx.x * 64, r0 = blockIdx.y * 64;
  int tid = threadIdx.x;
#pragma unroll
  for (int i = 0; i < 4; i++) {
    int idx = tid + i * 256;
    int row = idx >> 4;
    int c4  = (idx & 15) * 4;
    float4 v = *(const float4*)&in[(size_t)(r0 + row) * C + c0 + c4];
    tile[row][c4 + 0] = v.x; tile[row][c4 + 1] = v.y;
    tile[row][c4 + 2] = v.z; tile[row][c4 + 3] = v.w;
  }
  __syncthreads();
#pragma unroll
  for (int i = 0; i < 4; i++) {
    int idx = tid + i * 256;
    int col = idx >> 4;
    int r4  = (idx & 15) * 4;
    bf16x4 o;
    o[0] = (__bf16)tile[r4 + 0][col];
    o[1] = (__bf16)tile[r4 + 1][col];
    o[2] = (__bf16)tile[r4 + 2][col];
    o[3] = (__bf16)tile[r4 + 3][col];
    *(bf16x4*)&out[(size_t)(c0 + col) * R + r0 + r4] = o;
  }
}

__global__ __launch_bounds__(256) void concat_bias(const float* __restrict__ bq,
                                                   const float* __restrict__ bk,
                                                   const float* __restrict__ bv,
                                                   float* __restrict__ bcat) {
  int i = blockIdx.x * 256 + threadIdx.x;
  if (i < 3072) {
    float v = (i < 2048) ? bq[i] : (i < 2560 ? bk[i - 2048] : bv[i - 2560]);
    bcat[i] = v;
  }
}

// ---------------- GEMM: C[M][N] = A[M][K] * Bt[N][K]^T + bias ----------------
// 128x128 tile, BK=32, 4 waves, global_load_lds staging (m97 structure).
// MODE 1: fused QKV epilogue (Q prescaled by 0.125*log2e; V transposed AND
//         key-permuted: storage key index = swap(bits 2,3) of true key, so the
//         attention kernel's natural 16B loads yield the MFMA slot order).
// MODE 2: f32 row-major out.
template <int MODE>
__global__ __launch_bounds__(256) void gemm_bt(const __bf16* __restrict__ A,
                                               const __bf16* __restrict__ Bt,
                                               const float* __restrict__ bias,
                                               void* __restrict__ out0,
                                               __bf16* __restrict__ outK,
                                               __bf16* __restrict__ outV,
                                               int M, int N, int K) {
  __shared__ __bf16 As[128 * 32];
  __shared__ __bf16 Bs[128 * 32];
  int tid  = threadIdx.x;
  int lane = tid & 63, wave = tid >> 6;
  int wr = wave >> 1, wc = wave & 1;
  int la = lane & 15, kg = lane >> 4;
  int m0 = blockIdx.x * 128, n0 = blockIdx.y * 128;

  f32x4 acc[4][4];
#pragma unroll
  for (int i = 0; i < 4; i++)
#pragma unroll
    for (int j = 0; j < 4; j++)
#pragma unroll
      for (int r = 0; r < 4; r++) acc[i][j][r] = 0.f;

  int s0 = tid, s1 = tid + 256;
  const __bf16* ga0 = A  + (size_t)(m0 + (s0 >> 2)) * K + (s0 & 3) * 8;
  const __bf16* ga1 = A  + (size_t)(m0 + (s1 >> 2)) * K + (s1 & 3) * 8;
  const __bf16* gb0 = Bt + (size_t)(n0 + (s0 >> 2)) * K + (s0 & 3) * 8;
  const __bf16* gb1 = Bt + (size_t)(n0 + (s1 >> 2)) * K + (s1 & 3) * 8;
  __bf16* lA0 = As + (size_t)(0 * 256 + wave * 64) * 8;
  __bf16* lA1 = As + (size_t)(1 * 256 + wave * 64) * 8;
  __bf16* lB0 = Bs + (size_t)(0 * 256 + wave * 64) * 8;
  __bf16* lB1 = Bs + (size_t)(1 * 256 + wave * 64) * 8;

  for (int k0 = 0; k0 < K; k0 += 32) {
    gload16(ga0 + k0, lA0);
    gload16(ga1 + k0, lA1);
    gload16(gb0 + k0, lB0);
    gload16(gb1 + k0, lB1);
    __syncthreads();
    bf16x8 af[4], bfr[4];
#pragma unroll
    for (int i = 0; i < 4; i++) af[i]  = *(const bf16x8*)&As[(size_t)(wr * 64 + i * 16 + la) * 32 + kg * 8];
#pragma unroll
    for (int j = 0; j < 4; j++) bfr[j] = *(const bf16x8*)&Bs[(size_t)(wc * 64 + j * 16 + la) * 32 + kg * 8];
#pragma unroll
    for (int i = 0; i < 4; i++)
#pragma unroll
      for (int j = 0; j < 4; j++)
        acc[i][j] = __builtin_amdgcn_mfma_f32_16x16x32_bf16(af[i], bfr[j], acc[i][j], 0, 0, 0);
    __syncthreads();
  }

  int kgsw = ((kg & 1) << 1) | (kg >> 1);   // swap bits of kg: key-perm for V storage
#pragma unroll
  for (int i = 0; i < 4; i++) {
    int rowb  = m0 + wr * 64 + i * 16 + kg * 4;
    int rowbV = m0 + wr * 64 + i * 16 + kgsw * 4;
#pragma unroll
    for (int j = 0; j < 4; j++) {
      int col = n0 + wc * 64 + j * 16 + la;
      float bv = bias[col];
#pragma unroll
      for (int r = 0; r < 4; r++) {
        float v = acc[i][j][r] + bv;
        if (MODE == 2) {
          ((float*)out0)[(size_t)(rowb + r) * N + col] = v;
        } else {
          if (n0 < 2048)      ((__bf16*)out0)[(size_t)(rowb + r) * 2048 + col] = (__bf16)(v * 0.18033688f);
          else if (n0 < 2560) outK[(size_t)(rowb + r) * 512 + (col - 2048)] = (__bf16)v;
          else                outV[(size_t)(col - 2560) * M + rowbV + r] = (__bf16)v;
        }
      }
    }
  }
}

// ---------------- flash GQA attention, swapped-operand 32x32 ----------------
// 2 waves/block; each wave processes the causal-balanced q-tile PAIR (pi, 63-pi)
// sequentially -> uniform 65-step runtime for every wave (no drain tail).
// S^T = mfma(K,Q) (Q prescaled by 0.125*log2e). PV: Y^T = mfma(V^T, P^T) where
// V^T storage is key-permuted (bits 2<->3) so each lane's own s[0..15] pack
// IS the B-fragment (zero cross-lane redistribution), V loads stay 4x16B.
__global__ __launch_bounds__(128) void attn_kernel(const __bf16* __restrict__ Q,
                                                   const __bf16* __restrict__ K,
                                                   const __bf16* __restrict__ Vt,
                                                   __bf16* __restrict__ Y) {
  __shared__ __bf16 Ylds[2][32][72];
  const int M = B_SZ * T_SEQ;
  int tid = threadIdx.x;
  int wv = tid >> 6, l = tid & 63;
  int qcol = l & 31, hh = l >> 5;
  // XCD-contiguous swizzle: each XCD gets 8 consecutive heads (K/V L2-resident)
  int g = blockIdx.x;
  int swz = (g & 7) * 128 + (g >> 3);
  int bh = swz >> 4, pi2 = swz & 15;
  int pi = pi2 * 2 + wv;            // 0..31: this wave's pair index
  int b = bh >> 5, hq = bh & 31, kvh = hq >> 2;

  const __bf16* kbase = K + (size_t)(b * T_SEQ + qcol) * KV_DIM + kvh * 64 + hh * 8;
  const __bf16* vb0 = Vt + (size_t)(kvh * 64 + qcol) * M + (size_t)b * T_SEQ + hh * 8;
  const __bf16* vb1 = vb0 + (size_t)32 * M;
  __bf16 (*slab)[72] = Ylds[wv];

  for (int halfi = 0; halfi < 2; ++halfi) {
    int qt = halfi ? (63 - pi) : pi;
    int q0 = qt * 32;

    const __bf16* qrow = Q + (size_t)(b * T_SEQ + q0 + qcol) * C_EMB + hq * 64;
    bf16x8 qf[4];
#pragma unroll
    for (int c = 0; c < 4; c++) qf[c] = *(const bf16x8*)(qrow + c * 16 + hh * 8);

    f32x16 acc0, acc1;
#pragma unroll
    for (int r = 0; r < 16; r++) { acc0[r] = 0.f; acc1[r] = 0.f; }
    float m_run = -1e30f, l_run = 0.f;

    bf16x8 kf[4];
#pragma unroll
    for (int c = 0; c < 4; c++) kf[c] = *(const bf16x8*)(kbase + c * 16);

    for (int kb = 0; kb <= q0; kb += 32) {
      // ---- S^T[32k x 32q] over d=64
      f32x16 s;
#pragma unroll
      for (int r = 0; r < 16; r++) s[r] = 0.f;
      __builtin_amdgcn_s_setprio(1);
#pragma unroll
      for (int c = 0; c < 4; c++)
        s = __builtin_amdgcn_mfma_f32_32x32x16_bf16(kf[c], qf[c], s, 0, 0, 0);
      __builtin_amdgcn_s_setprio(0);
      // ---- prefetch next K tile (clamped; wasted only on last iter)
      {
        int nkb = (kb + 32 <= q0) ? kb + 32 : 0;
        const __bf16* nk = kbase + (size_t)nkb * KV_DIM;
#pragma unroll
        for (int c = 0; c < 4; c++) kf[c] = *(const bf16x8*)(nk + c * 16);
      }
      // ---- V loads: 4x16B, natural addresses (permutation baked into storage)
      bf16x8 vf0 = *(const bf16x8*)(vb0 + kb);
      bf16x8 vf1 = *(const bf16x8*)(vb0 + kb + 16);
      bf16x8 vf2 = *(const bf16x8*)(vb1 + kb);
      bf16x8 vf3 = *(const bf16x8*)(vb1 + kb + 16);
      // ---- causal mask (diagonal tile only)
      if (kb == q0) {
#pragma unroll
        for (int r = 0; r < 16; r++) {
          int kr = (r & 3) + 8 * (r >> 2) + 4 * hh;
          s[r] = (kr <= qcol) ? s[r] : -1e30f;
        }
      }
      // ---- row max: in-register tree + one cross-half shuffle
      float m01 = fmaxf(s[0], s[1]),  m23 = fmaxf(s[2], s[3]);
      float m45 = fmaxf(s[4], s[5]),  m67 = fmaxf(s[6], s[7]);
      float m89 = fmaxf(s[8], s[9]),  mab = fmaxf(s[10], s[11]);
      float mcd = fmaxf(s[12], s[13]), mef = fmaxf(s[14], s[15]);
      float mloc = fmaxf(fmaxf(fmaxf(m01, m23), fmaxf(m45, m67)),
                         fmaxf(fmaxf(m89, mab), fmaxf(mcd, mef)));
      mloc = fmaxf(mloc, __shfl_xor(mloc, 32, 64));
      // ---- deferred rescale (log2 domain; p <= 2^6)
      if (__any(mloc > m_run + 6.0f)) {
        float mnew = fmaxf(m_run, mloc);
        float corr = exp2f(m_run - mnew);
        l_run *= corr;
#pragma unroll
        for (int r = 0; r < 16; r++) { acc0[r] *= corr; acc1[r] *= corr; }
        m_run = mnew;
      }
      // ---- P = exp2(s - m); tree partial row sum (finished in epilogue)
#pragma unroll
      for (int r = 0; r < 16; r++) s[r] = exp2f(s[r] - m_run);
      l_run += (((s[0] + s[1]) + (s[2] + s[3])) + ((s[4] + s[5]) + (s[6] + s[7])))
             + (((s[8] + s[9]) + (s[10] + s[11])) + ((s[12] + s[13]) + (s[14] + s[15])));
      // ---- pack own 16 P-values straight into the two B-fragments (no shuffles)
      union { u32 u[4]; bf16x8 v; } w0u, w1u;
#pragma unroll
      for (int j = 0; j < 4; j++) {
        union { __bf16 b2[2]; u32 u; } p0, p1;
        p0.b2[0] = (__bf16)s[2 * j];     p0.b2[1] = (__bf16)s[2 * j + 1];
        p1.b2[0] = (__bf16)s[8 + 2 * j]; p1.b2[1] = (__bf16)s[9 + 2 * j];
        w0u.u[j] = p0.u;
        w1u.u[j] = p1.u;
      }
      // ---- PV: Y^T += V^T * P^T (slot order consistent via storage perm)
      __builtin_amdgcn_s_setprio(1);
      acc0 = __builtin_amdgcn_mfma_f32_32x32x16_bf16(vf0, w0u.v, acc0, 0, 0, 0);
      acc0 = __builtin_amdgcn_mfma_f32_32x32x16_bf16(vf1, w1u.v, acc0, 0, 0, 0);
      acc1 = __builtin_amdgcn_mfma_f32_32x32x16_bf16(vf2, w0u.v, acc1, 0, 0, 0);
      acc1 = __builtin_amdgcn_mfma_f32_32x32x16_bf16(vf3, w1u.v, acc1, 0, 0, 0);
      __builtin_amdgcn_s_setprio(0);
    }

    // ---- finish row sum across halves, normalize, LDS transpose, 16B stores
    l_run += __shfl_xor(l_run, 32, 64);
    float inv = 1.0f / l_run;
#pragma unroll
    for (int r = 0; r < 16; r++) {
      int drow = (r & 3) + 8 * (r >> 2) + 4 * hh;
      slab[qcol][drow]      = (__bf16)(acc0[r] * inv);
      slab[qcol][32 + drow] = (__bf16)(acc1[r] * inv);
    }
    // per-wave slab: wave-synchronous LDS, compiler inserts lgkmcnt waits
    __bf16* yrow = Y + (size_t)(b * T_SEQ + q0 + qcol) * C_EMB + hq * 64 + hh * 32;
#pragma unroll
    for (int c = 0; c < 4; c++)
      *(bf16x8*)(yrow + c * 8) = *(const bf16x8*)&slab[qcol][hh * 32 + c * 8];
  }
}

// ---------------- launch ----------------
extern "C" void kernel_launch(void* const* d_in, const int* in_sizes, int n_in,
                              void* d_out, int out_size, void* d_ws, size_t ws_size,
                              hipStream_t stream) {
  const float* x  = (const float*)d_in[0];
  const float* Wq = (const float*)d_in[1];
  const float* bq = (const float*)d_in[2];
  const float* Wk = (const float*)d_in[3];
  const float* bk = (const float*)d_in[4];
  const float* Wv = (const float*)d_in[5];
  const float* bv = (const float*)d_in[6];
  const float* Wo = (const float*)d_in[7];
  const float* bo = (const float*)d_in[8];
  float* out = (float*)d_out;

  const int M = B_SZ * T_SEQ;       // 4096

  char* w = (char*)d_ws;
  __bf16* xb   = (__bf16*)w; w += (size_t)M * C_EMB * 2;
  __bf16* Wall = (__bf16*)w; w += (size_t)3072 * C_EMB * 2;   // [Wq^T; Wk^T; Wv^T]
  __bf16* Wot  = (__bf16*)w; w += (size_t)C_EMB * C_EMB * 2;
  float*  bcat = (float*)w;  w += (size_t)3072 * 4;
  __bf16* qb   = (__bf16*)w; w += (size_t)M * C_EMB * 2;
  __bf16* kbf  = (__bf16*)w; w += (size_t)M * KV_DIM * 2;
  __bf16* vbt  = (__bf16*)w; w += (size_t)KV_DIM * M * 2;
  __bf16* yb   = (__bf16*)w; w += (size_t)M * C_EMB * 2;

  cast_f32_bf16<<<(M * C_EMB / 8 + 255) / 256, 256, 0, stream>>>(x, xb, M * C_EMB / 8);

  transpose_cast_kernel<<<dim3(C_EMB / 64, C_EMB / 64), 256, 0, stream>>>(Wq, Wall, C_EMB, C_EMB);
  transpose_cast_kernel<<<dim3(KV_DIM / 64, C_EMB / 64), 256, 0, stream>>>(Wk, Wall + (size_t)2048 * C_EMB, C_EMB, KV_DIM);
  transpose_cast_kernel<<<dim3(KV_DIM / 64, C_EMB / 64), 256, 0, stream>>>(Wv, Wall + (size_t)2560 * C_EMB, C_EMB, KV_DIM);
  transpose_cast_kernel<<<dim3(C_EMB / 64, C_EMB / 64), 256, 0, stream>>>(Wo, Wot, C_EMB, C_EMB);
  concat_bias<<<12, 256, 0, stream>>>(bq, bk, bv, bcat);

  // fused QKV projection: [4096 x 3072] = xb * Wall^T
  gemm_bt<1><<<dim3(M / 128, 3072 / 128), 256, 0, stream>>>(xb, Wall, bcat, qb, kbf, vbt, M, 3072, C_EMB);

  attn_kernel<<<dim3(1024), 128, 0, stream>>>(qb, kbf, vbt, yb);

  gemm_bt<2><<<dim3(M / 128, C_EMB / 128), 256, 0, stream>>>(yb, Wot, bo, out, nullptr, nullptr, M, C_EMB, C_EMB);
}